// Round 7
// baseline (7246.292 us; speedup 1.0000x reference)
//
#include <hip/hip_runtime.h>
#include <cstdint>
#include <cstddef>
#include <math.h>

// ---------------------------------------------------------------------------
// RTRBM forward, CD-2 Gibbs, bit-exact JAX threefry (partitionable mode).
// Round 7: software-pipelined mega-launch chain. Each of 68 sequential
// launches carries 5 block-roles on disjoint block ranges:
//   [0,512)   serial recurrence step t (fp64 U@r + sample h_t)
//   [512,544) stage2 @ t-1: vm bits = bern(sig(W^T h))        (i8 MFMA)
//   [544,552) stage3 @ t-2: h2 bits = bern(sig(W vm + hb64))  (i8 MFMA)
//   [552,584) stage4 @ t-3: v_model = bern(sig(W^T h2))       (i8 MFMA)
//   [584,592) Wv @ t+1: W @ v_t slice into fp64 WvT           (i8 MFMA)
// All stage work hides inside the serial chain's launch-latency slots.
// 5 i8 weight slices (scale 2^-40, logit err <= 1.9e-9). NO cooperative
// sync (round-6 lesson: grid.sync flushes L2 -> 74 us/step).
// ---------------------------------------------------------------------------

#define NVV 4096
#define NHH 1024
#define TT  64
#define BB  32
#define CC  2048
#define NSL 5

typedef int v4i  __attribute__((ext_vector_type(4)));
typedef int v16i __attribute__((ext_vector_type(16)));

__constant__ double SC5[NSL] = {0x1p-40, 0x1p-32, 0x1p-24, 0x1p-16, 0x1p-8};

__host__ __device__ __forceinline__ void tf2x32(uint32_t k0, uint32_t k1,
                                                uint32_t x0, uint32_t x1,
                                                uint32_t& o0, uint32_t& o1) {
  uint32_t ks2 = k0 ^ k1 ^ 0x1BD11BDAu;
#define TF_RND(r) { x0 += x1; x1 = (x1 << (r)) | (x1 >> (32 - (r))); x1 ^= x0; }
  x0 += k0; x1 += k1;
  TF_RND(13) TF_RND(15) TF_RND(26) TF_RND(6)
  x0 += k1;  x1 += ks2 + 1u;
  TF_RND(17) TF_RND(29) TF_RND(16) TF_RND(24)
  x0 += ks2; x1 += k0 + 2u;
  TF_RND(13) TF_RND(15) TF_RND(26) TF_RND(6)
  x0 += k0;  x1 += k1 + 3u;
  TF_RND(17) TF_RND(29) TF_RND(16) TF_RND(24)
  x0 += k1;  x1 += ks2 + 4u;
  TF_RND(13) TF_RND(15) TF_RND(26) TF_RND(6)
  x0 += ks2; x1 += k0 + 5u;
#undef TF_RND
  o0 = x0; o1 = x1;
}

__device__ __forceinline__ float tf_uniform(uint32_t k0, uint32_t k1, uint32_t j) {
  uint32_t o0, o1;
  tf2x32(k0, k1, 0u, j, o0, o1);
  uint32_t bits = o0 ^ o1;
  return __uint_as_float((bits >> 9) | 0x3f800000u) - 1.0f;
}

__device__ __forceinline__ void bern_sample(double logit, uint32_t k0, uint32_t k1,
                                            uint32_t j, float& p32, float& bit) {
  double pd = 1.0 / (1.0 + exp(-logit));
  p32 = (float)pd;
  float u = tf_uniform(k0, k1, j);
  bit = (u < p32) ? 1.0f : 0.0f;
}

// ck = split(key_t, 4)[phase]; key_t = t ? split(ks,63)[t-1] : k0
__device__ __forceinline__ void step_key(int t, int phase,
                                         uint32_t rk00, uint32_t rk01,
                                         uint32_t rk10, uint32_t rk11,
                                         uint32_t& c0, uint32_t& c1) {
  uint32_t kt0, kt1;
  tf2x32(rk10, rk11, 0u, (uint32_t)(t > 0 ? t - 1 : 0), kt0, kt1);
  if (t == 0) { kt0 = rk00; kt1 = rk01; }
  tf2x32(kt0, kt1, 0u, (uint32_t)phase, c0, c1);
}

// exact 5-byte signed decomposition of w*2^40 (|w| < 0.4)
__device__ __forceinline__ void slice5W(float w, signed char sb[NSL]) {
  long long v = __double2ll_rn((double)w * 0x1p40);
#pragma unroll
  for (int s = 0; s < NSL; s++) {
    signed char b = (signed char)(v & 0xFF);
    sb[s] = b;
    v = (v - b) >> 8;
  }
}

// ---------------------------------------------------------------------------
// Prep: W [1024][4096] f32 -> Ws[5][1024][4096] i8 and WsT[5][4096][1024] i8
__global__ __launch_bounds__(256)
void prepW(const float* __restrict__ W, signed char* __restrict__ Ws,
           signed char* __restrict__ WsT) {
  __shared__ float tl[64][65];
  int bi = blockIdx.x >> 6;
  int bj = blockIdx.x & 63;
  int n0 = bi * 64, k0 = bj * 64;
  int tid = threadIdx.x;
#pragma unroll
  for (int it = 0; it < 4; it++) {
    int r = (tid >> 4) + it * 16, c4 = (tid & 15) * 4;
    float4 q = *(const float4*)(W + (size_t)(n0 + r) * NVV + k0 + c4);
    tl[r][c4] = q.x; tl[r][c4 + 1] = q.y; tl[r][c4 + 2] = q.z; tl[r][c4 + 3] = q.w;
  }
  __syncthreads();
#pragma unroll
  for (int it = 0; it < 4; it++) {
    int r = (tid >> 4) + it * 16, c4 = (tid & 15) * 4;
    unsigned int pk[NSL] = {0, 0, 0, 0, 0};
    for (int j = 0; j < 4; j++) {
      signed char sb[NSL]; slice5W(tl[r][c4 + j], sb);
      for (int s = 0; s < NSL; s++) pk[s] |= ((unsigned)(unsigned char)sb[s]) << (8 * j);
    }
    for (int s = 0; s < NSL; s++)
      *(unsigned int*)(Ws + (size_t)s * NHH * NVV + (size_t)(n0 + r) * NVV + k0 + c4) = pk[s];
  }
#pragma unroll
  for (int it = 0; it < 4; it++) {
    int r = (tid >> 4) + it * 16, c4 = (tid & 15) * 4;
    unsigned int pk[NSL] = {0, 0, 0, 0, 0};
    for (int j = 0; j < 4; j++) {
      signed char sb[NSL]; slice5W(tl[c4 + j][r], sb);
      for (int s = 0; s < NSL; s++) pk[s] |= ((unsigned)(unsigned char)sb[s]) << (8 * j);
    }
    for (int s = 0; s < NSL; s++)
      *(unsigned int*)(WsT + (size_t)s * NVV * NHH + (size_t)(k0 + r) * NHH + n0 + c4) = pk[s];
  }
}

// Prep: v [4096][2048] f32 bits -> vT [2048][4096] i8
__global__ __launch_bounds__(256)
void prepVT(const float* __restrict__ v, signed char* __restrict__ vT) {
  __shared__ float tl[64][65];
  int bi = blockIdx.x >> 5;
  int bj = blockIdx.x & 31;
  int i0 = bi * 64, c0 = bj * 64;
  int tid = threadIdx.x;
#pragma unroll
  for (int it = 0; it < 4; it++) {
    int r = (tid >> 4) + it * 16, c4 = (tid & 15) * 4;
    float4 q = *(const float4*)(v + (size_t)(i0 + r) * CC + c0 + c4);
    tl[r][c4] = q.x; tl[r][c4 + 1] = q.y; tl[r][c4 + 2] = q.z; tl[r][c4 + 3] = q.w;
  }
  __syncthreads();
#pragma unroll
  for (int it = 0; it < 4; it++) {
    int cc = (tid >> 4) + it * 16, i4 = (tid & 15) * 4;
    unsigned int pk = 0;
    for (int j = 0; j < 4; j++)
      pk |= ((unsigned)(tl[i4 + j][cc] != 0.0f ? 1 : 0)) << (8 * j);
    *(unsigned int*)(vT + (size_t)(c0 + cc) * NVV + i0 + i4) = pk;
  }
}

// ---------------------------------------------------------------------------
// Pipelined mega-kernel: 5 roles on disjoint block ranges (see header).
__global__ __launch_bounds__(256)
void pipe(const float* __restrict__ U, double* __restrict__ WvT,
          const float* __restrict__ b_h, const float* __restrict__ b_init,
          const float* __restrict__ b_v,
          float* __restrict__ rt, unsigned char* __restrict__ hT,
          unsigned char* __restrict__ h2T, double* __restrict__ hb64,
          float* __restrict__ r_cmp,
          const signed char* __restrict__ vT, const signed char* __restrict__ Ws,
          const signed char* __restrict__ WsT, signed char* __restrict__ vmT,
          float* __restrict__ rmodel, float* __restrict__ vmodel,
          int t, uint32_t rk00, uint32_t rk01, uint32_t rk10, uint32_t rk11) {
  int blk = blockIdx.x;
  int tid = threadIdx.x;

  if (blk < 512) {
    // ---- role 0: serial recurrence step t ----
    if (t < 0 || t >= TT) return;
    __shared__ double red[2][4][32];
    int b = tid & 31, ks = (tid >> 5) & 3, rr = tid >> 7;
    int n = blk * 2 + rr;
    const float* rin = r_cmp + ((t + 1) & 1) * (NHH * BB);
    double a0 = 0, a1 = 0, a2 = 0, a3 = 0;
    if (t > 0) {
      const float* urow = U + (size_t)n * NHH + ks * 256;
      const float* rp = rin + b;
      for (int k = 0; k < 256; k += 4) {
        float4 uq = *(const float4*)(urow + k);
        int kk = (ks * 256 + k) * 32;
        a0 += (double)uq.x * (double)rp[kk];
        a1 += (double)uq.y * (double)rp[kk + 32];
        a2 += (double)uq.z * (double)rp[kk + 64];
        a3 += (double)uq.w * (double)rp[kk + 96];
      }
    }
    red[rr][ks][b] = (a0 + a1) + (a2 + a3);
    __syncthreads();
    if (ks == 0) {
      double s = red[rr][0][b] + red[rr][1][b] + red[rr][2][b] + red[rr][3][b];
      double hbv = (t > 0) ? (s + (double)b_h[n]) : (double)b_init[n];
      int c = t * 32 + b;
      double wv = WvT[(size_t)c * NHH + n];
      uint32_t ck0, ck1;
      step_key(t, 0, rk00, rk01, rk10, rk11, ck0, ck1);
      float p32, bit;
      bern_sample(wv + hbv, ck0, ck1, (uint32_t)(n * 32 + b), p32, bit);
      rt[(size_t)n * CC + c] = p32;
      hT[(size_t)c * NHH + n] = (unsigned char)(bit != 0.0f ? 1 : 0);
      hb64[(size_t)c * NHH + n] = hbv;
      r_cmp[(t & 1) * (NHH * BB) + n * 32 + b] = p32;
    }
    return;
  }

  int wave = tid >> 6, lane = tid & 63;
  int lrow = lane & 31, lhalf = lane >> 5;

  if (blk < 544) {
    // ---- role 1: stage2 @ tp = t-1 : vm bits = bern(sig(W^T h + b_v)) ----
    int tp = t - 1;
    if (tp < 0 || tp >= TT) return;
    int beta = blk - 512;
    int m0 = beta * 128 + wave * 32;    // i
    int n0 = tp * 32;                   // c base
    v16i acc[NSL];
    for (int s = 0; s < NSL; s++) for (int e = 0; e < 16; e++) acc[s][e] = 0;
    const signed char* aB = WsT + (size_t)(m0 + lrow) * NHH + 16 * lhalf;
    const signed char* bB = (const signed char*)hT + (size_t)(n0 + lrow) * NHH + 16 * lhalf;
#pragma unroll 2
    for (int kb = 0; kb < NHH; kb += 32) {
      v4i bf = *(const v4i*)(bB + kb);
#pragma unroll
      for (int s = 0; s < NSL; s++) {
        v4i af = *(const v4i*)(aB + (size_t)s * NVV * NHH + kb);
        acc[s] = __builtin_amdgcn_mfma_i32_32x32x32_i8(af, bf, acc[s], 0, 0, 0);
      }
    }
    uint32_t ck0, ck1;
    step_key(tp, 1, rk00, rk01, rk10, rk11, ck0, ck1);
    int c = n0 + lrow;
#pragma unroll
    for (int g = 0; g < 4; g++) {
      unsigned int packed = 0;
#pragma unroll
      for (int q = 0; q < 4; q++) {
        int e = g * 4 + q;
        int i = m0 + q + 8 * g + 4 * lhalf;
        double lg = (double)b_v[i];
#pragma unroll
        for (int s = 0; s < NSL; s++) lg += (double)acc[s][e] * SC5[s];
        float p32, bit;
        bern_sample(lg, ck0, ck1, (uint32_t)(i * 32 + lrow), p32, bit);
        (void)p32;
        packed |= ((unsigned)(bit != 0.0f ? 1 : 0)) << (8 * q);
      }
      *(unsigned int*)(vmT + (size_t)c * NVV + m0 + 8 * g + 4 * lhalf) = packed;
    }
    return;
  }

  if (blk < 552) {
    // ---- role 2: stage3 @ tp = t-2 : h2 = bern(sig(W vm + hb64)) ----
    int tp = t - 2;
    if (tp < 0 || tp >= TT) return;
    int beta = blk - 544;
    int n0 = beta * 128 + wave * 32;    // n
    int m0 = tp * 32;                   // c base
    v16i acc[NSL];
    for (int s = 0; s < NSL; s++) for (int e = 0; e < 16; e++) acc[s][e] = 0;
    const signed char* aB = vmT + (size_t)(m0 + lrow) * NVV + 16 * lhalf;
    const signed char* bB = Ws + (size_t)(n0 + lrow) * NVV + 16 * lhalf;
#pragma unroll 2
    for (int kb = 0; kb < NVV; kb += 32) {
      v4i af = *(const v4i*)(aB + kb);
#pragma unroll
      for (int s = 0; s < NSL; s++) {
        v4i bf = *(const v4i*)(bB + (size_t)s * NHH * NVV + kb);
        acc[s] = __builtin_amdgcn_mfma_i32_32x32x32_i8(af, bf, acc[s], 0, 0, 0);
      }
    }
    uint32_t ck0, ck1;
    step_key(tp, 2, rk00, rk01, rk10, rk11, ck0, ck1);
    int n = n0 + lrow;
#pragma unroll
    for (int e = 0; e < 16; e++) {
      int row = (e & 3) + 8 * (e >> 2) + 4 * lhalf;
      int c = m0 + row;
      double lg = 0;
#pragma unroll
      for (int s = 0; s < NSL; s++) lg += (double)acc[s][e] * SC5[s];
      lg += hb64[(size_t)c * NHH + n];
      float p32, bit;
      bern_sample(lg, ck0, ck1, (uint32_t)(n * 32 + row), p32, bit);
      (void)p32;
      h2T[(size_t)c * NHH + n] = (unsigned char)(bit != 0.0f ? 1 : 0);
      rmodel[(size_t)n * CC + c] = bit;
    }
    return;
  }

  if (blk < 584) {
    // ---- role 3: stage4 @ tp = t-3 : v_model = bern(sig(W^T h2 + b_v)) ----
    int tp = t - 3;
    if (tp < 0 || tp >= TT) return;
    int beta = blk - 552;
    int m0 = beta * 128 + wave * 32;    // i
    int n0 = tp * 32;                   // c base
    v16i acc[NSL];
    for (int s = 0; s < NSL; s++) for (int e = 0; e < 16; e++) acc[s][e] = 0;
    const signed char* aB = WsT + (size_t)(m0 + lrow) * NHH + 16 * lhalf;
    const signed char* bB = (const signed char*)h2T + (size_t)(n0 + lrow) * NHH + 16 * lhalf;
#pragma unroll 2
    for (int kb = 0; kb < NHH; kb += 32) {
      v4i bf = *(const v4i*)(bB + kb);
#pragma unroll
      for (int s = 0; s < NSL; s++) {
        v4i af = *(const v4i*)(aB + (size_t)s * NVV * NHH + kb);
        acc[s] = __builtin_amdgcn_mfma_i32_32x32x32_i8(af, bf, acc[s], 0, 0, 0);
      }
    }
    uint32_t ck0, ck1;
    step_key(tp, 3, rk00, rk01, rk10, rk11, ck0, ck1);
    int c = n0 + lrow;
#pragma unroll
    for (int e = 0; e < 16; e++) {
      int i = m0 + (e & 3) + 8 * (e >> 2) + 4 * lhalf;
      double lg = (double)b_v[i];
#pragma unroll
      for (int s = 0; s < NSL; s++) lg += (double)acc[s][e] * SC5[s];
      float p32, bit;
      bern_sample(lg, ck0, ck1, (uint32_t)(i * 32 + lrow), p32, bit);
      (void)p32;
      vmodel[(size_t)i * CC + c] = bit;
    }
    return;
  }

  {
    // ---- role 4: Wv slice @ tp = t+1 : WvT[c][n] = (v^T W^T) fp64 ----
    int tp = t + 1;
    if (tp < 0 || tp >= TT) return;
    int beta = blk - 584;
    int n0 = beta * 128 + wave * 32;    // n
    int m0 = tp * 32;                   // c base
    v16i acc[NSL];
    for (int s = 0; s < NSL; s++) for (int e = 0; e < 16; e++) acc[s][e] = 0;
    const signed char* aB = vT + (size_t)(m0 + lrow) * NVV + 16 * lhalf;
    const signed char* bB = Ws + (size_t)(n0 + lrow) * NVV + 16 * lhalf;
#pragma unroll 2
    for (int kb = 0; kb < NVV; kb += 32) {
      v4i af = *(const v4i*)(aB + kb);
#pragma unroll
      for (int s = 0; s < NSL; s++) {
        v4i bf = *(const v4i*)(bB + (size_t)s * NHH * NVV + kb);
        acc[s] = __builtin_amdgcn_mfma_i32_32x32x32_i8(af, bf, acc[s], 0, 0, 0);
      }
    }
    int n = n0 + lrow;
#pragma unroll
    for (int e = 0; e < 16; e++) {
      int row = (e & 3) + 8 * (e >> 2) + 4 * lhalf;
      int c = m0 + row;
      double lg = 0;
#pragma unroll
      for (int s = 0; s < NSL; s++) lg += (double)acc[s][e] * SC5[s];
      WvT[(size_t)c * NHH + n] = lg;
    }
    return;
  }
}

// ---------------------------------------------------------------------------
static void tf_split(const uint32_t key[2], int n, uint32_t out[][2]) {
  for (int i = 0; i < n; i++)
    tf2x32(key[0], key[1], 0u, (uint32_t)i, out[i][0], out[i][1]);
}

extern "C" void kernel_launch(void* const* d_in, const int* in_sizes, int n_in,
                              void* d_out, int out_size, void* d_ws, size_t ws_size,
                              hipStream_t stream) {
  const float* v      = (const float*)d_in[0];
  const float* W      = (const float*)d_in[1];
  const float* U      = (const float*)d_in[2];
  const float* b_v    = (const float*)d_in[3];
  const float* b_h    = (const float*)d_in[4];
  const float* b_init = (const float*)d_in[5];

  float* out    = (float*)d_out;
  float* vmodel = out;                           // [4096][2048]
  float* rmodel = out + (size_t)NVV * CC;        // [1024][2048]
  float* rt     = rmodel + (size_t)NHH * CC;     // [1024][2048]

  char* wsb = (char*)d_ws;
  signed char* Ws   = (signed char*)wsb;                         // 20 MB
  signed char* WsT  = (signed char*)(wsb + 20971520);            // 20 MB
  signed char* vT   = (signed char*)(wsb + 41943040);            // 8 MB
  signed char* vmT  = (signed char*)(wsb + 50331648);            // 8 MB
  unsigned char* hT = (unsigned char*)(wsb + 58720256);          // 2 MB
  unsigned char* h2T= (unsigned char*)(wsb + 60817408);          // 2 MB
  double* WvT       = (double*)(wsb + 62914560);                 // 16 MB
  double* hb64      = (double*)(wsb + 79691776);                 // 16 MB
  float* r_cmp      = (float*)(wsb + 96468992);                  // 256 KB

  uint32_t root[2] = {0u, 42u};
  uint32_t rk[2][2];  tf_split(root, 2, rk);

  // --- prep ---
  hipLaunchKernelGGL(prepW, dim3(1024), dim3(256), 0, stream, W, Ws, WsT);
  hipLaunchKernelGGL(prepVT, dim3(2048), dim3(256), 0, stream, v, vT);

  // --- pipelined chain: t = -1 (Wv@0 only) .. 66 (stage4@63) ---
  for (int t = -1; t <= TT + 2; t++) {
    hipLaunchKernelGGL(pipe, dim3(592), dim3(256), 0, stream,
                       U, WvT, b_h, b_init, b_v,
                       rt, hT, h2T, hb64, r_cmp,
                       vT, Ws, WsT, vmT, rmodel, vmodel,
                       t, rk[0][0], rk[0][1], rk[1][0], rk[1][1]);
  }

  (void)in_sizes; (void)n_in; (void)out_size; (void)ws_size;
}

// Round 8
// 1716.223 us; speedup vs baseline: 4.2222x; 4.2222x over previous
//
#include <hip/hip_runtime.h>
#include <cstdint>
#include <cstddef>
#include <math.h>

// ---------------------------------------------------------------------------
// RTRBM forward, CD-2 Gibbs, bit-exact JAX threefry (partitionable mode).
// Round 8: round-5 structure (batched stage GEMMs — round-7 lesson: per-t
// slicing re-streams weights 68x) + latency-oriented GEMM rework:
//   - 1 32x32 tile/wave (acc 80 regs), 4 waves share the 5-slice weight
//     operand via L1; weight-group index in low block bits -> same XCD L2.
//   - explicit 2-chunk register double-buffer (12 loads in flight/wave).
//   - 5 i8 slices (scale 2^-40; exact, validated round 6).
//   - step1: b-major r (float4 loads), 256 blocks x 4 rows.
// No cooperative sync (round-6 lesson: grid.sync L2-flush = 74 us/step).
// ---------------------------------------------------------------------------

#define NVV 4096
#define NHH 1024
#define TT  64
#define BB  32
#define CC  2048
#define NSL 5

typedef int v4i  __attribute__((ext_vector_type(4)));
typedef int v16i __attribute__((ext_vector_type(16)));

__constant__ double SC5[NSL] = {0x1p-40, 0x1p-32, 0x1p-24, 0x1p-16, 0x1p-8};

__host__ __device__ __forceinline__ void tf2x32(uint32_t k0, uint32_t k1,
                                                uint32_t x0, uint32_t x1,
                                                uint32_t& o0, uint32_t& o1) {
  uint32_t ks2 = k0 ^ k1 ^ 0x1BD11BDAu;
#define TF_RND(r) { x0 += x1; x1 = (x1 << (r)) | (x1 >> (32 - (r))); x1 ^= x0; }
  x0 += k0; x1 += k1;
  TF_RND(13) TF_RND(15) TF_RND(26) TF_RND(6)
  x0 += k1;  x1 += ks2 + 1u;
  TF_RND(17) TF_RND(29) TF_RND(16) TF_RND(24)
  x0 += ks2; x1 += k0 + 2u;
  TF_RND(13) TF_RND(15) TF_RND(26) TF_RND(6)
  x0 += k0;  x1 += k1 + 3u;
  TF_RND(17) TF_RND(29) TF_RND(16) TF_RND(24)
  x0 += k1;  x1 += ks2 + 4u;
  TF_RND(13) TF_RND(15) TF_RND(26) TF_RND(6)
  x0 += ks2; x1 += k0 + 5u;
#undef TF_RND
  o0 = x0; o1 = x1;
}

__device__ __forceinline__ float tf_uniform(uint32_t k0, uint32_t k1, uint32_t j) {
  uint32_t o0, o1;
  tf2x32(k0, k1, 0u, j, o0, o1);
  uint32_t bits = o0 ^ o1;
  return __uint_as_float((bits >> 9) | 0x3f800000u) - 1.0f;
}

__device__ __forceinline__ void bern_sample(double logit, uint32_t k0, uint32_t k1,
                                            uint32_t j, float& p32, float& bit) {
  double pd = 1.0 / (1.0 + exp(-logit));
  p32 = (float)pd;
  float u = tf_uniform(k0, k1, j);
  bit = (u < p32) ? 1.0f : 0.0f;
}

__device__ __forceinline__ void step_key(int t, int phase,
                                         uint32_t rk00, uint32_t rk01,
                                         uint32_t rk10, uint32_t rk11,
                                         uint32_t& c0, uint32_t& c1) {
  uint32_t kt0, kt1;
  tf2x32(rk10, rk11, 0u, (uint32_t)(t > 0 ? t - 1 : 0), kt0, kt1);
  if (t == 0) { kt0 = rk00; kt1 = rk01; }
  tf2x32(kt0, kt1, 0u, (uint32_t)phase, c0, c1);
}

__device__ __forceinline__ void slice5W(float w, signed char sb[NSL]) {
  long long v = __double2ll_rn((double)w * 0x1p40);
#pragma unroll
  for (int s = 0; s < NSL; s++) {
    signed char b = (signed char)(v & 0xFF);
    sb[s] = b;
    v = (v - b) >> 8;
  }
}

// ---------------------------------------------------------------------------
// Prep: W [1024][4096] f32 -> Ws[5][1024][4096] i8 and WsT[5][4096][1024] i8
__global__ __launch_bounds__(256)
void prepW(const float* __restrict__ W, signed char* __restrict__ Ws,
           signed char* __restrict__ WsT) {
  __shared__ float tl[64][65];
  int bi = blockIdx.x >> 6;
  int bj = blockIdx.x & 63;
  int n0 = bi * 64, k0 = bj * 64;
  int tid = threadIdx.x;
#pragma unroll
  for (int it = 0; it < 4; it++) {
    int r = (tid >> 4) + it * 16, c4 = (tid & 15) * 4;
    float4 q = *(const float4*)(W + (size_t)(n0 + r) * NVV + k0 + c4);
    tl[r][c4] = q.x; tl[r][c4 + 1] = q.y; tl[r][c4 + 2] = q.z; tl[r][c4 + 3] = q.w;
  }
  __syncthreads();
#pragma unroll
  for (int it = 0; it < 4; it++) {
    int r = (tid >> 4) + it * 16, c4 = (tid & 15) * 4;
    unsigned int pk[NSL] = {0, 0, 0, 0, 0};
    for (int j = 0; j < 4; j++) {
      signed char sb[NSL]; slice5W(tl[r][c4 + j], sb);
      for (int s = 0; s < NSL; s++) pk[s] |= ((unsigned)(unsigned char)sb[s]) << (8 * j);
    }
    for (int s = 0; s < NSL; s++)
      *(unsigned int*)(Ws + (size_t)s * NHH * NVV + (size_t)(n0 + r) * NVV + k0 + c4) = pk[s];
  }
#pragma unroll
  for (int it = 0; it < 4; it++) {
    int r = (tid >> 4) + it * 16, c4 = (tid & 15) * 4;
    unsigned int pk[NSL] = {0, 0, 0, 0, 0};
    for (int j = 0; j < 4; j++) {
      signed char sb[NSL]; slice5W(tl[c4 + j][r], sb);
      for (int s = 0; s < NSL; s++) pk[s] |= ((unsigned)(unsigned char)sb[s]) << (8 * j);
    }
    for (int s = 0; s < NSL; s++)
      *(unsigned int*)(WsT + (size_t)s * NVV * NHH + (size_t)(k0 + r) * NHH + n0 + c4) = pk[s];
  }
}

// Prep: v [4096][2048] f32 bits -> vT [2048][4096] i8
__global__ __launch_bounds__(256)
void prepVT(const float* __restrict__ v, signed char* __restrict__ vT) {
  __shared__ float tl[64][65];
  int bi = blockIdx.x >> 5;
  int bj = blockIdx.x & 31;
  int i0 = bi * 64, c0 = bj * 64;
  int tid = threadIdx.x;
#pragma unroll
  for (int it = 0; it < 4; it++) {
    int r = (tid >> 4) + it * 16, c4 = (tid & 15) * 4;
    float4 q = *(const float4*)(v + (size_t)(i0 + r) * CC + c0 + c4);
    tl[r][c4] = q.x; tl[r][c4 + 1] = q.y; tl[r][c4 + 2] = q.z; tl[r][c4 + 3] = q.w;
  }
  __syncthreads();
#pragma unroll
  for (int it = 0; it < 4; it++) {
    int cc = (tid >> 4) + it * 16, i4 = (tid & 15) * 4;
    unsigned int pk = 0;
    for (int j = 0; j < 4; j++)
      pk |= ((unsigned)(tl[i4 + j][cc] != 0.0f ? 1 : 0)) << (8 * j);
    *(unsigned int*)(vT + (size_t)(c0 + cc) * NVV + i0 + i4) = pk;
  }
}

// ---------------------------------------------------------------------------
// K-loop with 2-chunk register double-buffer. A = 1 stream, B = 5 slices.
#define KLOOP(KTOT, APTR, BPTR, BOFF)                                          \
  {                                                                            \
    v4i aA, bA[NSL], aB, bB[NSL];                                              \
    aA = *(const v4i*)(APTR);                                                  \
    _Pragma("unroll")                                                          \
    for (int s = 0; s < NSL; s++) bA[s] = *(const v4i*)(BPTR + (size_t)s * BOFF); \
    for (int kb = 0; kb < KTOT; kb += 64) {                                    \
      aB = *(const v4i*)(APTR + kb + 32);                                      \
      _Pragma("unroll")                                                        \
      for (int s = 0; s < NSL; s++)                                            \
        bB[s] = *(const v4i*)(BPTR + (size_t)s * BOFF + kb + 32);              \
      _Pragma("unroll")                                                        \
      for (int s = 0; s < NSL; s++)                                            \
        acc[s] = __builtin_amdgcn_mfma_i32_32x32x32_i8(aA, bA[s], acc[s], 0, 0, 0); \
      if (kb + 64 < KTOT) {                                                    \
        aA = *(const v4i*)(APTR + kb + 64);                                    \
        _Pragma("unroll")                                                      \
        for (int s = 0; s < NSL; s++)                                          \
          bA[s] = *(const v4i*)(BPTR + (size_t)s * BOFF + kb + 64);            \
      }                                                                        \
      _Pragma("unroll")                                                        \
      for (int s = 0; s < NSL; s++)                                            \
        acc[s] = __builtin_amdgcn_mfma_i32_32x32x32_i8(aB, bB[s], acc[s], 0, 0, 0); \
    }                                                                          \
  }

// Stage 0: WvT[c][n] = recombine(vT @ Ws^T). M=2048(c), N=1024(n), K=4096.
// Block: 128c x 32n; wave w owns c-subtile w. bn in low block bits (XCD/L2).
__global__ __launch_bounds__(256, 3)
void s0k(const signed char* __restrict__ vT, const signed char* __restrict__ Ws,
         double* __restrict__ WvT) {
  int wave = threadIdx.x >> 6, lane = threadIdx.x & 63;
  int lrow = lane & 31, lhalf = lane >> 5;
  int bn = blockIdx.x & 31, bm = blockIdx.x >> 5;     // 32 n-groups, 16 m-groups
  int m0 = bm * 128 + wave * 32;                       // c
  int n0 = bn * 32;                                    // n

  v16i acc[NSL];
  for (int s = 0; s < NSL; s++) for (int e = 0; e < 16; e++) acc[s][e] = 0;

  const signed char* aP = vT + (size_t)(m0 + lrow) * NVV + 16 * lhalf;
  const signed char* bP = Ws + (size_t)(n0 + lrow) * NVV + 16 * lhalf;
  KLOOP(NVV, aP, bP, (size_t)NHH * NVV)

#pragma unroll
  for (int e = 0; e < 16; e++) {
    int row = (e & 3) + 8 * (e >> 2) + 4 * lhalf;
    double lg = 0;
#pragma unroll
    for (int s = 0; s < NSL; s++) lg += (double)acc[s][e] * SC5[s];
    WvT[(size_t)(m0 + row) * NHH + n0 + lrow] = lg;
  }
}

// Serial step t: logit = WvT + hid_bias; sample h, r; store hb64.
// 256 blocks x 4 rows; threads = 32 b x 8 ks; r is b-major [2][32][1024].
__global__ __launch_bounds__(256)
void step1(const float* __restrict__ U, const float* __restrict__ rbuf,
           const double* __restrict__ WvT,
           const float* __restrict__ b_h, const float* __restrict__ b_init,
           float* __restrict__ rt, unsigned char* __restrict__ hT,
           double* __restrict__ hb64, int t, uint32_t key0, uint32_t key1) {
  __shared__ double red[4][32][8];
  int tid = threadIdx.x;
  int b = tid & 31, ks = tid >> 5;          // ks 0..7, k-chunk 128
  int n0 = blockIdx.x * 4;
  double acc[4] = {0, 0, 0, 0};
  if (t > 0) {
    const float* rp = rbuf + ((t + 1) & 1) * (BB * NHH) + b * NHH + ks * 128;
    const float* u0 = U + (size_t)n0 * NHH + ks * 128;
#pragma unroll 2
    for (int k = 0; k < 128; k += 4) {
      float4 rq = *(const float4*)(rp + k);
      double r0 = rq.x, r1 = rq.y, r2 = rq.z, r3 = rq.w;
#pragma unroll
      for (int r = 0; r < 4; r++) {
        float4 uq = *(const float4*)(u0 + (size_t)r * NHH + k);
        acc[r] += (double)uq.x * r0 + (double)uq.y * r1 +
                  (double)uq.z * r2 + (double)uq.w * r3;
      }
    }
  }
#pragma unroll
  for (int r = 0; r < 4; r++) red[r][b][ks] = acc[r];
  __syncthreads();
  if (tid < 128) {
    int rl = tid >> 5, b2 = tid & 31;
    int n = n0 + rl;
    double s = 0;
#pragma unroll
    for (int q = 0; q < 8; q++) s += red[rl][b2][q];
    double hbv = (t > 0) ? (s + (double)b_h[n]) : (double)b_init[n];
    int c = t * 32 + b2;
    double wv = WvT[(size_t)c * NHH + n];
    float p32, bit;
    bern_sample(wv + hbv, key0, key1, (uint32_t)(n * 32 + b2), p32, bit);
    rt[(size_t)n * CC + c] = p32;
    hT[(size_t)c * NHH + n] = (unsigned char)(bit != 0.0f ? 1 : 0);
    hb64[(size_t)c * NHH + n] = hbv;
    ((float*)rbuf)[(t & 1) * (BB * NHH) + b2 * NHH + n] = p32;
  }
}

// Stages 2/4: out[i][c] = bern(sig(W^T@x + b_v)). A=WsT(5), B=bits. K=1024.
// Block: 32i x 128c; wave w owns c-subtile w; bi in low bits (XCD/L2).
__global__ __launch_bounds__(256, 3)
void sV(const signed char* __restrict__ WsT, const signed char* __restrict__ xT,
        const float* __restrict__ b_v, unsigned char* __restrict__ bitT,
        float* __restrict__ f32out, int phase,
        uint32_t rk00, uint32_t rk01, uint32_t rk10, uint32_t rk11) {
  int wave = threadIdx.x >> 6, lane = threadIdx.x & 63;
  int lrow = lane & 31, lhalf = lane >> 5;
  int bi = blockIdx.x & 127, bc = blockIdx.x >> 7;    // 128 i-groups, 16 c-groups
  int m0 = bi * 32;                                    // i (shared by all waves)
  int c0 = bc * 128 + wave * 32;                       // c

  v16i acc[NSL];
  for (int s = 0; s < NSL; s++) for (int e = 0; e < 16; e++) acc[s][e] = 0;

  const signed char* aP = WsT + (size_t)(m0 + lrow) * NHH + 16 * lhalf;
  const signed char* bP = xT + (size_t)(c0 + lrow) * NHH + 16 * lhalf;
  // A/B roles swapped vs macro naming: here the 5-slice operand is aP.
  {
    v4i aA[NSL], bA, aB[NSL], bB;
#pragma unroll
    for (int s = 0; s < NSL; s++) aA[s] = *(const v4i*)(aP + (size_t)s * NVV * NHH);
    bA = *(const v4i*)(bP);
    for (int kb = 0; kb < NHH; kb += 64) {
#pragma unroll
      for (int s = 0; s < NSL; s++)
        aB[s] = *(const v4i*)(aP + (size_t)s * NVV * NHH + kb + 32);
      bB = *(const v4i*)(bP + kb + 32);
#pragma unroll
      for (int s = 0; s < NSL; s++)
        acc[s] = __builtin_amdgcn_mfma_i32_32x32x32_i8(aA[s], bA, acc[s], 0, 0, 0);
      if (kb + 64 < NHH) {
#pragma unroll
        for (int s = 0; s < NSL; s++)
          aA[s] = *(const v4i*)(aP + (size_t)s * NVV * NHH + kb + 64);
        bA = *(const v4i*)(bP + kb + 64);
      }
#pragma unroll
      for (int s = 0; s < NSL; s++)
        acc[s] = __builtin_amdgcn_mfma_i32_32x32x32_i8(aB[s], bB, acc[s], 0, 0, 0);
    }
  }

  int tt = c0 >> 5;
  uint32_t ck0, ck1;
  step_key(tt, phase, rk00, rk01, rk10, rk11, ck0, ck1);
  int c = c0 + lrow;
  if (bitT) {
#pragma unroll
    for (int g = 0; g < 4; g++) {
      unsigned int packed = 0;
#pragma unroll
      for (int q = 0; q < 4; q++) {
        int e = g * 4 + q;
        int i = m0 + q + 8 * g + 4 * lhalf;
        double lg = (double)b_v[i];
#pragma unroll
        for (int s = 0; s < NSL; s++) lg += (double)acc[s][e] * SC5[s];
        float p32, bit;
        bern_sample(lg, ck0, ck1, (uint32_t)(i * 32 + lrow), p32, bit);
        (void)p32;
        packed |= ((unsigned)(bit != 0.0f ? 1 : 0)) << (8 * q);
      }
      *(unsigned int*)(bitT + (size_t)c * NVV + m0 + 8 * g + 4 * lhalf) = packed;
    }
  } else {
#pragma unroll
    for (int e = 0; e < 16; e++) {
      int i = m0 + (e & 3) + 8 * (e >> 2) + 4 * lhalf;
      double lg = (double)b_v[i];
#pragma unroll
      for (int s = 0; s < NSL; s++) lg += (double)acc[s][e] * SC5[s];
      float p32, bit;
      bern_sample(lg, ck0, ck1, (uint32_t)(i * 32 + lrow), p32, bit);
      (void)p32;
      f32out[(size_t)i * CC + c] = bit;
    }
  }
}

// Stage 3: logit = W@vm + hb64; sample h2 -> h2T + rmodel (LDS-transposed).
// Block: 128c x 32n; wave w owns c-subtile w; bn in low bits (XCD/L2).
__global__ __launch_bounds__(256, 3)
void s3k(const signed char* __restrict__ vmT, const signed char* __restrict__ Ws,
         const double* __restrict__ hb64,
         unsigned char* __restrict__ h2T, float* __restrict__ rmodel,
         uint32_t rk00, uint32_t rk01, uint32_t rk10, uint32_t rk11) {
  __shared__ float tile[4][32][33];
  int wave = threadIdx.x >> 6, lane = threadIdx.x & 63;
  int lrow = lane & 31, lhalf = lane >> 5;
  int bn = blockIdx.x & 31, bm = blockIdx.x >> 5;
  int m0 = bm * 128 + wave * 32;   // c
  int n0 = bn * 32;                // n

  v16i acc[NSL];
  for (int s = 0; s < NSL; s++) for (int e = 0; e < 16; e++) acc[s][e] = 0;

  const signed char* aP = vmT + (size_t)(m0 + lrow) * NVV + 16 * lhalf;
  const signed char* bP = Ws + (size_t)(n0 + lrow) * NVV + 16 * lhalf;
  KLOOP(NVV, aP, bP, (size_t)NHH * NVV)

  int tt = m0 >> 5;
  uint32_t ck0, ck1;
  step_key(tt, 2, rk00, rk01, rk10, rk11, ck0, ck1);
  int n = n0 + lrow;
#pragma unroll
  for (int e = 0; e < 16; e++) {
    int row = (e & 3) + 8 * (e >> 2) + 4 * lhalf;
    int c = m0 + row;
    double lg = 0;
#pragma unroll
    for (int s = 0; s < NSL; s++) lg += (double)acc[s][e] * SC5[s];
    lg += hb64[(size_t)c * NHH + n];
    float p32, bit;
    bern_sample(lg, ck0, ck1, (uint32_t)(n * 32 + row), p32, bit);
    (void)p32;
    h2T[(size_t)c * NHH + n] = (unsigned char)(bit != 0.0f ? 1 : 0);
    tile[wave][lrow][row] = bit;     // [n_local][c_local]
  }
  __syncthreads();
#pragma unroll
  for (int j = 0; j < 16; j++) {
    int nl = j * 2 + lhalf;
    float val = tile[wave][nl][lrow];
    rmodel[(size_t)(n0 + nl) * CC + m0 + lrow] = val;
  }
}

// ---------------------------------------------------------------------------
static void tf_split(const uint32_t key[2], int n, uint32_t out[][2]) {
  for (int i = 0; i < n; i++)
    tf2x32(key[0], key[1], 0u, (uint32_t)i, out[i][0], out[i][1]);
}

extern "C" void kernel_launch(void* const* d_in, const int* in_sizes, int n_in,
                              void* d_out, int out_size, void* d_ws, size_t ws_size,
                              hipStream_t stream) {
  const float* v      = (const float*)d_in[0];
  const float* W      = (const float*)d_in[1];
  const float* U      = (const float*)d_in[2];
  const float* b_v    = (const float*)d_in[3];
  const float* b_h    = (const float*)d_in[4];
  const float* b_init = (const float*)d_in[5];

  float* out    = (float*)d_out;
  float* vmodel = out;                           // [4096][2048]
  float* rmodel = out + (size_t)NVV * CC;        // [1024][2048]
  float* rt     = rmodel + (size_t)NHH * CC;     // [1024][2048]

  char* wsb = (char*)d_ws;
  signed char* Ws   = (signed char*)wsb;                         // 20 MB
  signed char* WsT  = (signed char*)(wsb + 20971520);            // 20 MB
  signed char* vT   = (signed char*)(wsb + 41943040);            // 8 MB
  signed char* vmT  = (signed char*)(wsb + 50331648);            // 8 MB
  unsigned char* hT = (unsigned char*)(wsb + 58720256);          // 2 MB
  unsigned char* h2T= (unsigned char*)(wsb + 60817408);          // 2 MB
  double* WvT       = (double*)(wsb + 62914560);                 // 16 MB
  double* hb64      = (double*)(wsb + 79691776);                 // 16 MB
  float* rbuf       = (float*)(wsb + 96468992);                  // 256 KB

  uint32_t root[2] = {0u, 42u};
  uint32_t rk[2][2];  tf_split(root, 2, rk);
  uint32_t tk[63][2]; tf_split(rk[1], 63, tk);

  // --- prep ---
  hipLaunchKernelGGL(prepW, dim3(1024), dim3(256), 0, stream, W, Ws, WsT);
  hipLaunchKernelGGL(prepVT, dim3(2048), dim3(256), 0, stream, v, vT);

  // --- stage 0: WvT = W@v (all t) ---
  hipLaunchKernelGGL(s0k, dim3(512), dim3(256), 0, stream, vT, Ws, WvT);

  // --- stage 1: serial recurrence ---
  for (int t = 0; t < TT; t++) {
    uint32_t key_t0 = t ? tk[t - 1][0] : rk[0][0];
    uint32_t key_t1 = t ? tk[t - 1][1] : rk[0][1];
    uint32_t ck0, ck1;
    tf2x32(key_t0, key_t1, 0u, 0u, ck0, ck1);
    hipLaunchKernelGGL(step1, dim3(256), dim3(256), 0, stream,
                       U, rbuf, WvT, b_h, b_init, rt, hT, hb64, t, ck0, ck1);
  }

  // --- stage 2: vm bits -> vmT ---
  hipLaunchKernelGGL(sV, dim3(2048), dim3(256), 0, stream,
                     WsT, (const signed char*)hT, b_v, (unsigned char*)vmT,
                     (float*)nullptr, 1, rk[0][0], rk[0][1], rk[1][0], rk[1][1]);

  // --- stage 3: h2 bits + rmodel ---
  hipLaunchKernelGGL(s3k, dim3(512), dim3(256), 0, stream,
                     vmT, Ws, hb64, h2T, rmodel,
                     rk[0][0], rk[0][1], rk[1][0], rk[1][1]);

  // --- stage 4: vmodel ---
  hipLaunchKernelGGL(sV, dim3(2048), dim3(256), 0, stream,
                     WsT, (const signed char*)h2T, b_v, (unsigned char*)nullptr,
                     vmodel, 3, rk[0][0], rk[0][1], rk[1][0], rk[1][1]);

  (void)in_sizes; (void)n_in; (void)out_size; (void)ws_size;
}